// Round 10
// baseline (221.598 us; speedup 1.0000x reference)
//
#include <hip/hip_runtime.h>
#include <hip/hip_bf16.h>

#define EMB   1024
#define SEQ   2048
#define BATCH 4
#define NH    16
#define DHEAD 64
#define MROWS (BATCH*SEQ)   // 8192
#define NSTRIP (SEQ/32)     // 64
#define QSCALE 0.18033688011112042f  // 0.125 * log2(e): softmax in exp2 domain

typedef float f32x4  __attribute__((ext_vector_type(4)));
typedef float f32x16 __attribute__((ext_vector_type(16)));
typedef short s16x8  __attribute__((ext_vector_type(8)));

__device__ __forceinline__ f32x4 mfma16(s16x8 a, s16x8 b, f32x4 c) {
    return __builtin_amdgcn_mfma_f32_16x16x32_bf16(a, b, c, 0, 0, 0);
}
__device__ __forceinline__ f32x16 mfma32(s16x8 a, s16x8 b, f32x16 c) {
    return __builtin_amdgcn_mfma_f32_32x32x16_bf16(a, b, c, 0, 0, 0);
}

__device__ __forceinline__ unsigned short f2bf(float f) {
    __hip_bfloat16 h = __float2bfloat16(f);
    return __builtin_bit_cast(unsigned short, h);
}

__device__ __forceinline__ unsigned cvtpk(float lo, float hi) {
    unsigned r;
    asm("v_cvt_pk_bf16_f32 %0, %1, %2" : "=v"(r) : "v"(lo), "v"(hi));
    return r;
}

__device__ __forceinline__ void plane_swap(unsigned &a, unsigned &b) {
    asm("v_permlane32_swap_b32 %0, %1" : "+v"(a), "+v"(b));
}

__device__ __forceinline__ s16x8 frag4(unsigned a, unsigned b, unsigned c, unsigned d) {
    union { unsigned u[4]; s16x8 f; } x;
    x.u[0] = a; x.u[1] = b; x.u[2] = c; x.u[3] = d;
    return x.f;
}

__device__ __forceinline__ float exp2r(float x) {   // raw v_exp_f32 (2^x)
    float r;
    asm("v_exp_f32 %0, %1" : "=v"(r) : "v"(x));
    return r;
}
__device__ __forceinline__ float max3f(float a, float b, float c) {
    float r;
    asm("v_max3_f32 %0, %1, %2, %3" : "=v"(r) : "v"(a), "v"(b), "v"(c));
    return r;
}

// ---------------- fp32 -> bf16 conversion: one launch for all 5 tensors ----------------
__global__ void cvt_all(const float* __restrict__ x,
                        const float* __restrict__ w0, const float* __restrict__ w1,
                        const float* __restrict__ w2, const float* __restrict__ w3,
                        unsigned short* __restrict__ xb,
                        unsigned short* __restrict__ o0, unsigned short* __restrict__ o1,
                        unsigned short* __restrict__ o2, unsigned short* __restrict__ o3,
                        int nx4, int nw4) {
    int i = blockIdx.x * blockDim.x + threadIdx.x;
    const float* in; unsigned short* out; int n;
    switch (blockIdx.y) {
        case 0:  in = x;  out = xb; n = nx4; break;
        case 1:  in = w0; out = o0; n = nw4; break;
        case 2:  in = w1; out = o1; n = nw4; break;
        case 3:  in = w2; out = o2; n = nw4; break;
        default: in = w3; out = o3; n = nw4; break;
    }
    if (i >= n) return;
    float4 v = reinterpret_cast<const float4*>(in)[i];
    ushort4 o;
    o.x = f2bf(v.x); o.y = f2bf(v.y); o.z = f2bf(v.z); o.w = f2bf(v.w);
    reinterpret_cast<ushort4*>(out)[i] = o;
}

#define GLDS(g, s) __builtin_amdgcn_global_load_lds((const __attribute__((address_space(1))) void*)(g), \
                       (__attribute__((address_space(3))) void*)(s), 16, 0, 0)

// ---------------- fused QKV GEMM (2-phase double-buffered staging) ----------------
// grid (24, 64): blockIdx.x = seg(0..2)*8 + n-tile; seg 0->Q, 1->K, 2->V.
__global__ __launch_bounds__(256) void gemm_qkv(const unsigned short* __restrict__ A,
                                                const unsigned short* __restrict__ wqb,
                                                const unsigned short* __restrict__ wkb,
                                                const unsigned short* __restrict__ wvb,
                                                const float* __restrict__ bq,
                                                const float* __restrict__ bk,
                                                const float* __restrict__ bv,
                                                unsigned short* __restrict__ qB,
                                                unsigned short* __restrict__ kB,
                                                unsigned short* __restrict__ vtB) {
    __shared__ unsigned short sA0[128*32];
    __shared__ unsigned short sB0[128*32];
    __shared__ unsigned short sA1[128*32];
    __shared__ unsigned short sB1[128*32];
    const int tid = threadIdx.x;
    const int w  = tid >> 6, l = tid & 63;
    const int lg = l >> 4,  lr = l & 15;
    const int nb  = blockIdx.x;
    const int seg = nb >> 3;
    const int mBase = blockIdx.y * 128;
    const int nBase = (nb & 7) * 128;
    const unsigned short* Bw = (seg == 0) ? wqb : (seg == 1) ? wkb : wvb;
    const float* bias = (seg == 0) ? bq : (seg == 1) ? bk : bv;
    const int wr = w >> 1, wc = w & 1;
    const int srow = l >> 2;
    const int sk0  = (l & 3) * 8;
    const bool segV = (seg == 2);

    f32x4 acc[4][4] = {};

    auto STAGE = [&](unsigned short* dA, unsigned short* dB, int kb) {
        #pragma unroll
        for (int rr = 0; rr < 2; ++rr) {
            const int chunk = w + rr * 4;                 // wave-uniform
            const unsigned short* ga = A  + (size_t)(mBase + chunk*16 + srow) * EMB + kb + sk0;
            GLDS(ga, &dA[chunk * 512]);
            const unsigned short* gb = Bw + (size_t)(nBase + chunk*16 + srow) * EMB + kb + sk0;
            GLDS(gb, &dB[chunk * 512]);
        }
    };
    auto COMPUTE = [&](const unsigned short* dA, const unsigned short* dB) {
        s16x8 af[4], bf[4];
        #pragma unroll
        for (int mi = 0; mi < 4; ++mi)
            af[mi] = *reinterpret_cast<const s16x8*>(&dA[(wr*64 + mi*16 + lr)*32 + lg*8]);
        #pragma unroll
        for (int ni = 0; ni < 4; ++ni)
            bf[ni] = *reinterpret_cast<const s16x8*>(&dB[(wc*64 + ni*16 + lr)*32 + lg*8]);
        if (segV) {
            #pragma unroll
            for (int mi = 0; mi < 4; ++mi)
                #pragma unroll
                for (int ni = 0; ni < 4; ++ni)
                    acc[ni][mi] = mfma16(bf[ni], af[mi], acc[ni][mi]);  // C^T
        } else {
            #pragma unroll
            for (int mi = 0; mi < 4; ++mi)
                #pragma unroll
                for (int ni = 0; ni < 4; ++ni)
                    acc[mi][ni] = mfma16(af[mi], bf[ni], acc[mi][ni]);
        }
    };

    STAGE(sA0, sB0, 0);
    __syncthreads();
    for (int kb = 0; kb < EMB; kb += 64) {
        STAGE(sA1, sB1, kb + 32);       // prefetch hides under COMPUTE
        COMPUTE(sA0, sB0);
        __syncthreads();                // drains mostly-complete prefetch
        if (kb + 64 < EMB) STAGE(sA0, sB0, kb + 64);
        COMPUTE(sA1, sB1);
        __syncthreads();
    }

    const int colBase = nBase + wc * 64;
    const int rowBase = mBase + wr * 64;
    if (!segV) {
        unsigned short* outp = seg ? kB : qB;
        const float oscale = seg ? 1.0f : QSCALE;
        #pragma unroll
        for (int ni = 0; ni < 4; ++ni) {
            const int col = colBase + ni*16 + lr;
            const float bv = bias[col];
            const int h = col >> 6, d = col & 63;
            const int inner = ((d >> 4) * 2 + ((d >> 3) & 1)) * 256 + (d & 7);
            #pragma unroll
            for (int mi = 0; mi < 4; ++mi) {
                #pragma unroll
                for (int r = 0; r < 4; ++r) {
                    const int gr = rowBase + mi*16 + lg*4 + r;
                    const int b = gr >> 11, sin_ = gr & 2047;
                    const int strip = sin_ >> 5, l31q = sin_ & 31;
                    outp[(size_t)(b*NH + h) * (SEQ*DHEAD) + strip*2048 + inner + l31q*8]
                        = f2bf((acc[mi][ni][r] + bv) * oscale);
                }
            }
        }
    } else {
        #pragma unroll
        for (int ni = 0; ni < 4; ++ni) {
            #pragma unroll
            for (int r = 0; r < 4; ++r) {
                const int n = colBase + ni*16 + lg*4 + r;
                const float bv = bias[n];
                const int h = n >> 6, d = n & 63;
                #pragma unroll
                for (int mi = 0; mi < 4; ++mi) {
                    const int tok = rowBase + mi*16 + lr;
                    const int b = tok >> 11, sv = tok & 2047;
                    const int kvt = sv >> 5, ks = (sv >> 4) & 1, hi2 = (sv >> 3) & 1, j = sv & 7;
                    vtB[(size_t)(b*NH + h) * (SEQ*DHEAD) + kvt*2048 + (ks*2 + hi2)*512 + d*8 + j]
                        = f2bf(acc[ni][mi][r] + bv);
                }
            }
        }
    }
}

// ---------------- output projection GEMM (2-phase, fp32 out + bias) ----------------
__global__ __launch_bounds__(256) void gemm_out(const unsigned short* __restrict__ A,
                                                const unsigned short* __restrict__ Bw,
                                                const float* __restrict__ bias,
                                                float* __restrict__ Out) {
    __shared__ unsigned short sA0[128*32];
    __shared__ unsigned short sB0[128*32];
    __shared__ unsigned short sA1[128*32];
    __shared__ unsigned short sB1[128*32];
    const int tid = threadIdx.x;
    const int w  = tid >> 6, l = tid & 63;
    const int lg = l >> 4,  lr = l & 15;
    const int mBase = blockIdx.y * 128;
    const int nBase = blockIdx.x * 128;
    const int wr = w >> 1, wc = w & 1;
    const int srow = l >> 2;
    const int sk0  = (l & 3) * 8;

    f32x4 acc[4][4] = {};

    auto STAGE = [&](unsigned short* dA, unsigned short* dB, int kb) {
        #pragma unroll
        for (int rr = 0; rr < 2; ++rr) {
            const int chunk = w + rr * 4;
            const unsigned short* ga = A  + (size_t)(mBase + chunk*16 + srow) * EMB + kb + sk0;
            GLDS(ga, &dA[chunk * 512]);
            const unsigned short* gb = Bw + (size_t)(nBase + chunk*16 + srow) * EMB + kb + sk0;
            GLDS(gb, &dB[chunk * 512]);
        }
    };
    auto COMPUTE = [&](const unsigned short* dA, const unsigned short* dB) {
        s16x8 af[4], bf[4];
        #pragma unroll
        for (int mi = 0; mi < 4; ++mi)
            af[mi] = *reinterpret_cast<const s16x8*>(&dA[(wr*64 + mi*16 + lr)*32 + lg*8]);
        #pragma unroll
        for (int ni = 0; ni < 4; ++ni)
            bf[ni] = *reinterpret_cast<const s16x8*>(&dB[(wc*64 + ni*16 + lr)*32 + lg*8]);
        #pragma unroll
        for (int mi = 0; mi < 4; ++mi)
            #pragma unroll
            for (int ni = 0; ni < 4; ++ni)
                acc[mi][ni] = mfma16(af[mi], bf[ni], acc[mi][ni]);
    };

    STAGE(sA0, sB0, 0);
    __syncthreads();
    for (int kb = 0; kb < EMB; kb += 64) {
        STAGE(sA1, sB1, kb + 32);
        COMPUTE(sA0, sB0);
        __syncthreads();
        if (kb + 64 < EMB) STAGE(sA0, sB0, kb + 64);
        COMPUTE(sA1, sB1);
        __syncthreads();
    }

    const int colBase = nBase + wc * 64;
    const int rowBase = mBase + wr * 64;
    #pragma unroll
    for (int ni = 0; ni < 4; ++ni) {
        const int col = colBase + ni*16 + lr;
        const float bv = bias[col];
        #pragma unroll
        for (int mi = 0; mi < 4; ++mi) {
            #pragma unroll
            for (int r = 0; r < 4; ++r) {
                const int gr = rowBase + mi*16 + lg*4 + r;
                Out[(size_t)gr * EMB + col] = acc[mi][ni][r] + bv;
            }
        }
    }
}

// ---------------- flash attention (causal), swapped-operand 32x32 MFMA ----------------
// 4 waves per block, all the SAME strip, DIFFERENT heads (bh = g*4 + wave) ->
// zero intra-block imbalance, 4 waves per workgroup slot.  1024 blocks; each
// 256-block round spans all strip depths (g = bx>>6, strip = bx&63).
__global__ __launch_bounds__(256) void attn_fwd(const unsigned short* __restrict__ qb,
                                                const unsigned short* __restrict__ kb,
                                                const unsigned short* __restrict__ vb,
                                                unsigned short* __restrict__ ctx) {
    __shared__ __align__(16) unsigned sld[4][32*36];
    const int tid = threadIdx.x;
    const int wv_ = tid >> 6;
    const int l = tid & 63;
    const int l31 = l & 31, hi = l >> 5;
    const int g = (int)blockIdx.x >> 6;              // 0..15 head-group
    const int strip = (int)blockIdx.x & 63;          // round spans all depths
    const int bh = g * 4 + wv_;
    const int q0 = strip * 32;
    const size_t hbase = (size_t)bh * SEQ * DHEAD;
    const unsigned short* qh = qb + hbase;
    const unsigned short* kh = kb + hbase;
    const unsigned short* vh = vb + hbase;

    s16x8 qf[4];
    #pragma unroll
    for (int s = 0; s < 4; ++s)
        qf[s] = *reinterpret_cast<const s16x8*>(&qh[strip*2048 + s*512 + l*8]);

    f32x16 o0 = {}, o1 = {};
    float m = -__builtin_inff(), lsum = 0.f;
    const int ntiles = strip + 1;

    s16x8 kfA[4], vfA[4], kfB[4], vfB[4];

    auto LOADKV = [&](s16x8* kf, s16x8* vf, int t) {
        const unsigned short* kp = kh + t*2048;
        #pragma unroll
        for (int s = 0; s < 4; ++s)
            kf[s] = *reinterpret_cast<const s16x8*>(&kp[s*512 + l*8]);
        const unsigned short* vp = vh + t*2048 + hi*512 + l31*8;
        #pragma unroll
        for (int ks = 0; ks < 2; ++ks) {
            vf[ks]     = *reinterpret_cast<const s16x8*>(&vp[ks*1024]);
            vf[2 + ks] = *reinterpret_cast<const s16x8*>(&vp[ks*1024 + 256]);
        }
    };

    auto BODY = [&](s16x8* kf, s16x8* vf, int t) {
        f32x16 sa = {};
        #pragma unroll
        for (int s = 0; s < 4; ++s) sa = mfma32(kf[s], qf[s], sa);

        if (t == strip) {  // diagonal tile: mask kv > q
            #pragma unroll
            for (int r = 0; r < 16; ++r) {
                const int kvloc = (r & 3) + 8*(r >> 2) + 4*hi;
                if (kvloc > l31) sa[r] = -__builtin_inff();
            }
        }

        const float a0 = max3f(sa[0],  sa[1],  sa[2]);
        const float a1 = max3f(sa[3],  sa[4],  sa[5]);
        const float a2 = max3f(sa[6],  sa[7],  sa[8]);
        const float a3 = max3f(sa[9],  sa[10], sa[11]);
        const float a4 = max3f(sa[12], sa[13], sa[14]);
        const float b0 = max3f(a0, a1, a2);
        const float b1 = max3f(a3, a4, sa[15]);
        float pm = fmaxf(b0, b1);
        pm = fmaxf(pm, __shfl_xor(pm, 32));

        float mn = m;
        if (!__all(pm <= m + 8.0f)) {        // T13 defer-max (log2 domain: p <= 256)
            mn = fmaxf(m, pm);
            const float fs = exp2r(m - mn);
            o0 *= fs; o1 *= fs; lsum *= fs;
            m = mn;
        }

        #pragma unroll
        for (int r = 0; r < 16; ++r) sa[r] = exp2r(sa[r] - mn);   // in-place

        const float s0 = sa[0]+sa[1],   s1 = sa[2]+sa[3],   s2 = sa[4]+sa[5],   s3 = sa[6]+sa[7];
        const float s4 = sa[8]+sa[9],   s5 = sa[10]+sa[11], s6 = sa[12]+sa[13], s7 = sa[14]+sa[15];
        const float t0 = s0+s1, t1 = s2+s3, t2 = s4+s5, t3 = s6+s7;
        float rs = (t0+t1) + (t2+t3);
        rs += __shfl_xor(rs, 32);
        lsum += rs;

        unsigned u[4], v[4];
        #pragma unroll
        for (int r2 = 0; r2 < 4; ++r2) {
            u[r2] = cvtpk(sa[4*r2 + 0], sa[4*r2 + 1]);
            v[r2] = cvtpk(sa[4*r2 + 2], sa[4*r2 + 3]);
        }
        plane_swap(u[0], u[1]); plane_swap(v[0], v[1]);
        plane_swap(u[2], u[3]); plane_swap(v[2], v[3]);
        const s16x8 pf0 = frag4(u[0], v[0], u[1], v[1]);
        const s16x8 pf1 = frag4(u[2], v[2], u[3], v[3]);

        o0 = mfma32(vf[0], pf0, o0);
        o0 = mfma32(vf[1], pf1, o0);
        o1 = mfma32(vf[2], pf0, o1);
        o1 = mfma32(vf[3], pf1, o1);
    };

    LOADKV(kfA, vfA, 0);
    int t = 0;
    for (; t + 1 < ntiles; t += 2) {
        LOADKV(kfB, vfB, t + 1);
        BODY(kfA, vfA, t);
        if (t + 2 < ntiles) LOADKV(kfA, vfA, t + 2);
        BODY(kfB, vfB, t + 1);
    }
    if (t < ntiles) BODY(kfA, vfA, t);

    // ---- epilogue: normalize, wave-local LDS transpose, coalesced store ----
    const float inv = 1.0f / lsum;
    unsigned* my = sld[wv_];
    #pragma unroll
    for (int dt = 0; dt < 2; ++dt) {
        #pragma unroll
        for (int r2 = 0; r2 < 4; ++r2) {
            const float e0 = (dt ? o1[4*r2+0] : o0[4*r2+0]) * inv;
            const float e1 = (dt ? o1[4*r2+1] : o0[4*r2+1]) * inv;
            const float e2 = (dt ? o1[4*r2+2] : o0[4*r2+2]) * inv;
            const float e3 = (dt ? o1[4*r2+3] : o0[4*r2+3]) * inv;
            const int col = 4*r2 + 2*hi + 16*dt;
            my[l31*36 + col]     = cvtpk(e0, e1);
            my[l31*36 + col + 1] = cvtpk(e2, e3);
        }
    }
    asm volatile("s_waitcnt lgkmcnt(0)" ::: "memory");
    __builtin_amdgcn_sched_barrier(0);
    const int row = l >> 1, half = l & 1;
    const unsigned* rp = &my[row*36 + half*16];
    const int b = bh >> 4, h = bh & 15;
    unsigned short* op = &ctx[((size_t)b*SEQ + q0 + row) * EMB + h*DHEAD + half*32];
    #pragma unroll
    for (int i = 0; i < 4; ++i) {
        uint4 d4 = *reinterpret_cast<const uint4*>(rp + i*4);
        *reinterpret_cast<uint4*>(op + i*8) = d4;
    }
}

// ---------------- launch ----------------
extern "C" void kernel_launch(void* const* d_in, const int* in_sizes, int n_in,
                              void* d_out, int out_size, void* d_ws, size_t ws_size,
                              hipStream_t stream) {
    const float* x  = (const float*)d_in[0];
    const float* wq = (const float*)d_in[1];
    const float* bq = (const float*)d_in[2];
    const float* wk = (const float*)d_in[3];
    const float* bk = (const float*)d_in[4];
    const float* wv = (const float*)d_in[5];
    const float* bv = (const float*)d_in[6];
    const float* wo = (const float*)d_in[7];
    const float* bo = (const float*)d_in[8];
    float* out = (float*)d_out;

    char* ws = (char*)d_ws;
    const size_t MB = 1ull << 20;
    unsigned short* xb  = (unsigned short*)(ws);            // 16 MB; reused as ctx later
    unsigned short* wqb = (unsigned short*)(ws + 16*MB);
    unsigned short* wkb = (unsigned short*)(ws + 18*MB);
    unsigned short* wvb = (unsigned short*)(ws + 20*MB);
    unsigned short* wob = (unsigned short*)(ws + 22*MB);
    unsigned short* qB  = (unsigned short*)(ws + 24*MB);    // fragment-ready, pre-scaled (exp2 domain)
    unsigned short* kB  = (unsigned short*)(ws + 40*MB);    // fragment-ready
    unsigned short* vtB = (unsigned short*)(ws + 56*MB);    // fragment-ready V^T
    unsigned short* ctx = xb;

    const int nx4 = MROWS * EMB / 4;
    const int nw4 = EMB * EMB / 4;
    cvt_all<<<dim3((nx4 + 255)/256, 5), 256, 0, stream>>>(x, wq, wk, wv, wo,
                                                          xb, wqb, wkb, wvb, wob, nx4, nw4);

    gemm_qkv<<<dim3(24, MROWS/128), 256, 0, stream>>>(xb, wqb, wkb, wvb, bq, bk, bv, qB, kB, vtB);

    attn_fwd<<<dim3(16 * NSTRIP), 256, 0, stream>>>(qB, kB, vtB, ctx);

    gemm_out<<<dim3(EMB/128, MROWS/128), 256, 0, stream>>>(ctx, wob, bo, out);
}

// Round 11
// 215.285 us; speedup vs baseline: 1.0293x; 1.0293x over previous
//
#include <hip/hip_runtime.h>
#include <hip/hip_bf16.h>

#define EMB   1024
#define SEQ   2048
#define BATCH 4
#define NH    16
#define DHEAD 64
#define MROWS (BATCH*SEQ)   // 8192
#define NSTRIP (SEQ/32)     // 64
#define QSCALE 0.18033688011112042f  // 0.125 * log2(e): softmax in exp2 domain

typedef float f32x4  __attribute__((ext_vector_type(4)));
typedef float f32x16 __attribute__((ext_vector_type(16)));
typedef short s16x8  __attribute__((ext_vector_type(8)));

__device__ __forceinline__ f32x4 mfma16(s16x8 a, s16x8 b, f32x4 c) {
    return __builtin_amdgcn_mfma_f32_16x16x32_bf16(a, b, c, 0, 0, 0);
}
__device__ __forceinline__ f32x16 mfma32(s16x8 a, s16x8 b, f32x16 c) {
    return __builtin_amdgcn_mfma_f32_32x32x16_bf16(a, b, c, 0, 0, 0);
}

__device__ __forceinline__ unsigned short f2bf(float f) {
    __hip_bfloat16 h = __float2bfloat16(f);
    return __builtin_bit_cast(unsigned short, h);
}

__device__ __forceinline__ unsigned cvtpk(float lo, float hi) {
    unsigned r;
    asm("v_cvt_pk_bf16_f32 %0, %1, %2" : "=v"(r) : "v"(lo), "v"(hi));
    return r;
}

__device__ __forceinline__ void plane_swap(unsigned &a, unsigned &b) {
    asm("v_permlane32_swap_b32 %0, %1" : "+v"(a), "+v"(b));
}

__device__ __forceinline__ s16x8 frag4(unsigned a, unsigned b, unsigned c, unsigned d) {
    union { unsigned u[4]; s16x8 f; } x;
    x.u[0] = a; x.u[1] = b; x.u[2] = c; x.u[3] = d;
    return x.f;
}

__device__ __forceinline__ float exp2r(float x) {   // raw v_exp_f32 (2^x)
    float r;
    asm("v_exp_f32 %0, %1" : "=v"(r) : "v"(x));
    return r;
}
__device__ __forceinline__ float max3f(float a, float b, float c) {
    float r;
    asm("v_max3_f32 %0, %1, %2, %3" : "=v"(r) : "v"(a), "v"(b), "v"(c));
    return r;
}

// ---------------- fp32 -> bf16 conversion: one launch for all 5 tensors ----------------
__global__ void cvt_all(const float* __restrict__ x,
                        const float* __restrict__ w0, const float* __restrict__ w1,
                        const float* __restrict__ w2, const float* __restrict__ w3,
                        unsigned short* __restrict__ xb,
                        unsigned short* __restrict__ o0, unsigned short* __restrict__ o1,
                        unsigned short* __restrict__ o2, unsigned short* __restrict__ o3,
                        int nx4, int nw4) {
    int i = blockIdx.x * blockDim.x + threadIdx.x;
    const float* in; unsigned short* out; int n;
    switch (blockIdx.y) {
        case 0:  in = x;  out = xb; n = nx4; break;
        case 1:  in = w0; out = o0; n = nw4; break;
        case 2:  in = w1; out = o1; n = nw4; break;
        case 3:  in = w2; out = o2; n = nw4; break;
        default: in = w3; out = o3; n = nw4; break;
    }
    if (i >= n) return;
    float4 v = reinterpret_cast<const float4*>(in)[i];
    ushort4 o;
    o.x = f2bf(v.x); o.y = f2bf(v.y); o.z = f2bf(v.z); o.w = f2bf(v.w);
    reinterpret_cast<ushort4*>(out)[i] = o;
}

#define GLDS(g, s) __builtin_amdgcn_global_load_lds((const __attribute__((address_space(1))) void*)(g), \
                       (__attribute__((address_space(3))) void*)(s), 16, 0, 0)

// ---------------- fused QKV GEMM (2-phase double-buffered staging) ----------------
// grid (24, 64): blockIdx.x = seg(0..2)*8 + n-tile; seg 0->Q, 1->K, 2->V.
__global__ __launch_bounds__(256) void gemm_qkv(const unsigned short* __restrict__ A,
                                                const unsigned short* __restrict__ wqb,
                                                const unsigned short* __restrict__ wkb,
                                                const unsigned short* __restrict__ wvb,
                                                const float* __restrict__ bq,
                                                const float* __restrict__ bk,
                                                const float* __restrict__ bv,
                                                unsigned short* __restrict__ qB,
                                                unsigned short* __restrict__ kB,
                                                unsigned short* __restrict__ vtB) {
    __shared__ unsigned short sA0[128*32];
    __shared__ unsigned short sB0[128*32];
    __shared__ unsigned short sA1[128*32];
    __shared__ unsigned short sB1[128*32];
    const int tid = threadIdx.x;
    const int w  = tid >> 6, l = tid & 63;
    const int lg = l >> 4,  lr = l & 15;
    const int nb  = blockIdx.x;
    const int seg = nb >> 3;
    const int mBase = blockIdx.y * 128;
    const int nBase = (nb & 7) * 128;
    const unsigned short* Bw = (seg == 0) ? wqb : (seg == 1) ? wkb : wvb;
    const float* bias = (seg == 0) ? bq : (seg == 1) ? bk : bv;
    const int wr = w >> 1, wc = w & 1;
    const int srow = l >> 2;
    const int sk0  = (l & 3) * 8;
    const bool segV = (seg == 2);

    f32x4 acc[4][4] = {};

    auto STAGE = [&](unsigned short* dA, unsigned short* dB, int kb) {
        #pragma unroll
        for (int rr = 0; rr < 2; ++rr) {
            const int chunk = w + rr * 4;                 // wave-uniform
            const unsigned short* ga = A  + (size_t)(mBase + chunk*16 + srow) * EMB + kb + sk0;
            GLDS(ga, &dA[chunk * 512]);
            const unsigned short* gb = Bw + (size_t)(nBase + chunk*16 + srow) * EMB + kb + sk0;
            GLDS(gb, &dB[chunk * 512]);
        }
    };
    auto COMPUTE = [&](const unsigned short* dA, const unsigned short* dB) {
        s16x8 af[4], bf[4];
        #pragma unroll
        for (int mi = 0; mi < 4; ++mi)
            af[mi] = *reinterpret_cast<const s16x8*>(&dA[(wr*64 + mi*16 + lr)*32 + lg*8]);
        #pragma unroll
        for (int ni = 0; ni < 4; ++ni)
            bf[ni] = *reinterpret_cast<const s16x8*>(&dB[(wc*64 + ni*16 + lr)*32 + lg*8]);
        if (segV) {
            #pragma unroll
            for (int mi = 0; mi < 4; ++mi)
                #pragma unroll
                for (int ni = 0; ni < 4; ++ni)
                    acc[ni][mi] = mfma16(bf[ni], af[mi], acc[ni][mi]);  // C^T
        } else {
            #pragma unroll
            for (int mi = 0; mi < 4; ++mi)
                #pragma unroll
                for (int ni = 0; ni < 4; ++ni)
                    acc[mi][ni] = mfma16(af[mi], bf[ni], acc[mi][ni]);
        }
    };

    STAGE(sA0, sB0, 0);
    __syncthreads();
    for (int kb = 0; kb < EMB; kb += 64) {
        STAGE(sA1, sB1, kb + 32);       // prefetch hides under COMPUTE
        COMPUTE(sA0, sB0);
        __syncthreads();                // drains mostly-complete prefetch
        if (kb + 64 < EMB) STAGE(sA0, sB0, kb + 64);
        COMPUTE(sA1, sB1);
        __syncthreads();
    }

    const int colBase = nBase + wc * 64;
    const int rowBase = mBase + wr * 64;
    if (!segV) {
        unsigned short* outp = seg ? kB : qB;
        const float oscale = seg ? 1.0f : QSCALE;
        #pragma unroll
        for (int ni = 0; ni < 4; ++ni) {
            const int col = colBase + ni*16 + lr;
            const float bv = bias[col];
            const int h = col >> 6, d = col & 63;
            const int inner = ((d >> 4) * 2 + ((d >> 3) & 1)) * 256 + (d & 7);
            #pragma unroll
            for (int mi = 0; mi < 4; ++mi) {
                #pragma unroll
                for (int r = 0; r < 4; ++r) {
                    const int gr = rowBase + mi*16 + lg*4 + r;
                    const int b = gr >> 11, sin_ = gr & 2047;
                    const int strip = sin_ >> 5, l31q = sin_ & 31;
                    outp[(size_t)(b*NH + h) * (SEQ*DHEAD) + strip*2048 + inner + l31q*8]
                        = f2bf((acc[mi][ni][r] + bv) * oscale);
                }
            }
        }
    } else {
        #pragma unroll
        for (int ni = 0; ni < 4; ++ni) {
            #pragma unroll
            for (int r = 0; r < 4; ++r) {
                const int n = colBase + ni*16 + lg*4 + r;
                const float bv = bias[n];
                const int h = n >> 6, d = n & 63;
                #pragma unroll
                for (int mi = 0; mi < 4; ++mi) {
                    const int tok = rowBase + mi*16 + lr;
                    const int b = tok >> 11, sv = tok & 2047;
                    const int kvt = sv >> 5, ks = (sv >> 4) & 1, hi2 = (sv >> 3) & 1, j = sv & 7;
                    vtB[(size_t)(b*NH + h) * (SEQ*DHEAD) + kvt*2048 + (ks*2 + hi2)*512 + d*8 + j]
                        = f2bf(acc[ni][mi][r] + bv);
                }
            }
        }
    }
}

// ---------------- output projection GEMM (2-phase, fp32 out + bias) ----------------
__global__ __launch_bounds__(256) void gemm_out(const unsigned short* __restrict__ A,
                                                const unsigned short* __restrict__ Bw,
                                                const float* __restrict__ bias,
                                                float* __restrict__ Out) {
    __shared__ unsigned short sA0[128*32];
    __shared__ unsigned short sB0[128*32];
    __shared__ unsigned short sA1[128*32];
    __shared__ unsigned short sB1[128*32];
    const int tid = threadIdx.x;
    const int w  = tid >> 6, l = tid & 63;
    const int lg = l >> 4,  lr = l & 15;
    const int mBase = blockIdx.y * 128;
    const int nBase = blockIdx.x * 128;
    const int wr = w >> 1, wc = w & 1;
    const int srow = l >> 2;
    const int sk0  = (l & 3) * 8;

    f32x4 acc[4][4] = {};

    auto STAGE = [&](unsigned short* dA, unsigned short* dB, int kb) {
        #pragma unroll
        for (int rr = 0; rr < 2; ++rr) {
            const int chunk = w + rr * 4;
            const unsigned short* ga = A  + (size_t)(mBase + chunk*16 + srow) * EMB + kb + sk0;
            GLDS(ga, &dA[chunk * 512]);
            const unsigned short* gb = Bw + (size_t)(nBase + chunk*16 + srow) * EMB + kb + sk0;
            GLDS(gb, &dB[chunk * 512]);
        }
    };
    auto COMPUTE = [&](const unsigned short* dA, const unsigned short* dB) {
        s16x8 af[4], bf[4];
        #pragma unroll
        for (int mi = 0; mi < 4; ++mi)
            af[mi] = *reinterpret_cast<const s16x8*>(&dA[(wr*64 + mi*16 + lr)*32 + lg*8]);
        #pragma unroll
        for (int ni = 0; ni < 4; ++ni)
            bf[ni] = *reinterpret_cast<const s16x8*>(&dB[(wc*64 + ni*16 + lr)*32 + lg*8]);
        #pragma unroll
        for (int mi = 0; mi < 4; ++mi)
            #pragma unroll
            for (int ni = 0; ni < 4; ++ni)
                acc[mi][ni] = mfma16(af[mi], bf[ni], acc[mi][ni]);
    };

    STAGE(sA0, sB0, 0);
    __syncthreads();
    for (int kb = 0; kb < EMB; kb += 64) {
        STAGE(sA1, sB1, kb + 32);
        COMPUTE(sA0, sB0);
        __syncthreads();
        if (kb + 64 < EMB) STAGE(sA0, sB0, kb + 64);
        COMPUTE(sA1, sB1);
        __syncthreads();
    }

    const int colBase = nBase + wc * 64;
    const int rowBase = mBase + wr * 64;
    #pragma unroll
    for (int ni = 0; ni < 4; ++ni) {
        const int col = colBase + ni*16 + lr;
        const float bv = bias[col];
        #pragma unroll
        for (int mi = 0; mi < 4; ++mi) {
            #pragma unroll
            for (int r = 0; r < 4; ++r) {
                const int gr = rowBase + mi*16 + lg*4 + r;
                Out[(size_t)gr * EMB + col] = acc[mi][ni][r] + bv;
            }
        }
    }
}

// ---------------- flash attention (causal), dual-strip swapped-operand 32x32 MFMA ----------------
// 1 wave per block; 2048 blocks.  Wave owns strips p AND 63-p (bh = bx&63 keeps the
// proven locality order).  K/V tile loads + addresses shared between both strips:
// every wave executes exactly 65 bodies -> perfect balance, half the loads.
__global__ __launch_bounds__(64) void attn_fwd(const unsigned short* __restrict__ qb,
                                               const unsigned short* __restrict__ kb,
                                               const unsigned short* __restrict__ vb,
                                               unsigned short* __restrict__ ctx) {
    __shared__ __align__(16) unsigned sld[2][32*36];
    const int l = threadIdx.x;
    const int l31 = l & 31, hi = l >> 5;
    const int bh = blockIdx.x & 63;
    const int pair = (int)blockIdx.x >> 6;          // 0..31
    const int sL = pair, sH = NSTRIP - 1 - pair;    // sL <= 31 < sH
    const size_t hbase = (size_t)bh * SEQ * DHEAD;
    const unsigned short* qh = qb + hbase;
    const unsigned short* kh = kb + hbase;
    const unsigned short* vh = vb + hbase;

    s16x8 qfL[4], qfH[4];
    #pragma unroll
    for (int s = 0; s < 4; ++s) {
        qfL[s] = *reinterpret_cast<const s16x8*>(&qh[sL*2048 + s*512 + l*8]);
        qfH[s] = *reinterpret_cast<const s16x8*>(&qh[sH*2048 + s*512 + l*8]);
    }

    f32x16 oL0 = {}, oL1 = {}, oH0 = {}, oH1 = {};
    float mL = -__builtin_inff(), lsL = 0.f;
    float mH = -__builtin_inff(), lsH = 0.f;
    const int ntiles = sH + 1;

    s16x8 kfA[4], vfA[4], kfB[4], vfB[4];

    auto LOADKV = [&](s16x8* kf, s16x8* vf, int t) {
        const unsigned short* kp = kh + t*2048;
        #pragma unroll
        for (int s = 0; s < 4; ++s)
            kf[s] = *reinterpret_cast<const s16x8*>(&kp[s*512 + l*8]);
        const unsigned short* vp = vh + t*2048 + hi*512 + l31*8;
        #pragma unroll
        for (int ks = 0; ks < 2; ++ks) {
            vf[ks]     = *reinterpret_cast<const s16x8*>(&vp[ks*1024]);
            vf[2 + ks] = *reinterpret_cast<const s16x8*>(&vp[ks*1024 + 256]);
        }
    };

    auto BODY = [&](const s16x8* kf, const s16x8* vf, const s16x8* qf,
                    f32x16& o0, f32x16& o1, float& m, float& lsum, int t, int strip) {
        f32x16 sa = {};
        #pragma unroll
        for (int s = 0; s < 4; ++s) sa = mfma32(kf[s], qf[s], sa);

        if (t == strip) {  // diagonal tile: mask kv > q
            #pragma unroll
            for (int r = 0; r < 16; ++r) {
                const int kvloc = (r & 3) + 8*(r >> 2) + 4*hi;
                if (kvloc > l31) sa[r] = -__builtin_inff();
            }
        }

        const float a0 = max3f(sa[0],  sa[1],  sa[2]);
        const float a1 = max3f(sa[3],  sa[4],  sa[5]);
        const float a2 = max3f(sa[6],  sa[7],  sa[8]);
        const float a3 = max3f(sa[9],  sa[10], sa[11]);
        const float a4 = max3f(sa[12], sa[13], sa[14]);
        const float b0 = max3f(a0, a1, a2);
        const float b1 = max3f(a3, a4, sa[15]);
        float pm = fmaxf(b0, b1);
        pm = fmaxf(pm, __shfl_xor(pm, 32));

        float mn = m;
        if (!__all(pm <= m + 8.0f)) {        // T13 defer-max (log2 domain: p <= 256)
            mn = fmaxf(m, pm);
            const float fs = exp2r(m - mn);
            o0 *= fs; o1 *= fs; lsum *= fs;
            m = mn;
        }

        #pragma unroll
        for (int r = 0; r < 16; ++r) sa[r] = exp2r(sa[r] - mn);   // in-place

        const float s0 = sa[0]+sa[1],   s1 = sa[2]+sa[3],   s2 = sa[4]+sa[5],   s3 = sa[6]+sa[7];
        const float s4 = sa[8]+sa[9],   s5 = sa[10]+sa[11], s6 = sa[12]+sa[13], s7 = sa[14]+sa[15];
        const float t0 = s0+s1, t1 = s2+s3, t2 = s4+s5, t3 = s6+s7;
        float rs = (t0+t1) + (t2+t3);
        rs += __shfl_xor(rs, 32);
        lsum += rs;

        unsigned u[4], v[4];
        #pragma unroll
        for (int r2 = 0; r2 < 4; ++r2) {
            u[r2] = cvtpk(sa[4*r2 + 0], sa[4*r2 + 1]);
            v[r2] = cvtpk(sa[4*r2 + 2], sa[4*r2 + 3]);
        }
        plane_swap(u[0], u[1]); plane_swap(v[0], v[1]);
        plane_swap(u[2], u[3]); plane_swap(v[2], v[3]);
        const s16x8 pf0 = frag4(u[0], v[0], u[1], v[1]);
        const s16x8 pf1 = frag4(u[2], v[2], u[3], v[3]);

        o0 = mfma32(vf[0], pf0, o0);
        o0 = mfma32(vf[1], pf1, o0);
        o1 = mfma32(vf[2], pf0, o1);
        o1 = mfma32(vf[3], pf1, o1);
    };

    auto STEP = [&](const s16x8* kf, const s16x8* vf, int t) {
        if (t <= sL) BODY(kf, vf, qfL, oL0, oL1, mL, lsL, t, sL);
        BODY(kf, vf, qfH, oH0, oH1, mH, lsH, t, sH);
    };

    LOADKV(kfA, vfA, 0);
    int t = 0;
    for (; t + 1 < ntiles; t += 2) {
        LOADKV(kfB, vfB, t + 1);
        STEP(kfA, vfA, t);
        if (t + 2 < ntiles) LOADKV(kfA, vfA, t + 2);
        STEP(kfB, vfB, t + 1);
    }
    if (t < ntiles) STEP(kfA, vfA, t);

    // ---- epilogue: normalize, wave-local LDS transpose, coalesced store (both strips) ----
    const int b = bh >> 4, h = bh & 15;
    auto EPI = [&](const f32x16& o0, const f32x16& o1, float lsum, int strip, unsigned* my) {
        const float inv = 1.0f / lsum;
        #pragma unroll
        for (int dt = 0; dt < 2; ++dt) {
            #pragma unroll
            for (int r2 = 0; r2 < 4; ++r2) {
                const float e0 = (dt ? o1[4*r2+0] : o0[4*r2+0]) * inv;
                const float e1 = (dt ? o1[4*r2+1] : o0[4*r2+1]) * inv;
                const float e2 = (dt ? o1[4*r2+2] : o0[4*r2+2]) * inv;
                const float e3 = (dt ? o1[4*r2+3] : o0[4*r2+3]) * inv;
                const int col = 4*r2 + 2*hi + 16*dt;
                my[l31*36 + col]     = cvtpk(e0, e1);
                my[l31*36 + col + 1] = cvtpk(e2, e3);
            }
        }
        asm volatile("s_waitcnt lgkmcnt(0)" ::: "memory");
        __builtin_amdgcn_sched_barrier(0);
        const int row = l >> 1, half = l & 1;
        const unsigned* rp = &my[row*36 + half*16];
        unsigned short* op = &ctx[((size_t)b*SEQ + strip*32 + row) * EMB + h*DHEAD + half*32];
        #pragma unroll
        for (int i = 0; i < 4; ++i) {
            uint4 d4 = *reinterpret_cast<const uint4*>(rp + i*4);
            *reinterpret_cast<uint4*>(op + i*8) = d4;
        }
    };
    EPI(oL0, oL1, lsL, sL, sld[0]);
    EPI(oH0, oH1, lsH, sH, sld[1]);
}

// ---------------- launch ----------------
extern "C" void kernel_launch(void* const* d_in, const int* in_sizes, int n_in,
                              void* d_out, int out_size, void* d_ws, size_t ws_size,
                              hipStream_t stream) {
    const float* x  = (const float*)d_in[0];
    const float* wq = (const float*)d_in[1];
    const float* bq = (const float*)d_in[2];
    const float* wk = (const float*)d_in[3];
    const float* bk = (const float*)d_in[4];
    const float* wv = (const float*)d_in[5];
    const float* bv = (const float*)d_in[6];
    const float* wo = (const float*)d_in[7];
    const float* bo = (const float*)d_in[8];
    float* out = (float*)d_out;

    char* ws = (char*)d_ws;
    const size_t MB = 1ull << 20;
    unsigned short* xb  = (unsigned short*)(ws);            // 16 MB; reused as ctx later
    unsigned short* wqb = (unsigned short*)(ws + 16*MB);
    unsigned short* wkb = (unsigned short*)(ws + 18*MB);
    unsigned short* wvb = (unsigned short*)(ws + 20*MB);
    unsigned short* wob = (unsigned short*)(ws + 22*MB);
    unsigned short* qB  = (unsigned short*)(ws + 24*MB);    // fragment-ready, pre-scaled (exp2 domain)
    unsigned short* kB  = (unsigned short*)(ws + 40*MB);    // fragment-ready
    unsigned short* vtB = (unsigned short*)(ws + 56*MB);    // fragment-ready V^T
    unsigned short* ctx = xb;

    const int nx4 = MROWS * EMB / 4;
    const int nw4 = EMB * EMB / 4;
    cvt_all<<<dim3((nx4 + 255)/256, 5), 256, 0, stream>>>(x, wq, wk, wv, wo,
                                                          xb, wqb, wkb, wvb, wob, nx4, nw4);

    gemm_qkv<<<dim3(24, MROWS/128), 256, 0, stream>>>(xb, wqb, wkb, wvb, bq, bk, bv, qB, kB, vtB);

    attn_fwd<<<dim3((NSTRIP/2) * BATCH * NH), 64, 0, stream>>>(qB, kB, vtB, ctx);

    gemm_out<<<dim3(EMB/128, MROWS/128), 256, 0, stream>>>(ctx, wob, bo, out);
}

// Round 12
// 186.125 us; speedup vs baseline: 1.1906x; 1.1567x over previous
//
#include <hip/hip_runtime.h>
#include <hip/hip_bf16.h>

#define EMB   1024
#define SEQ   2048
#define BATCH 4
#define NH    16
#define DHEAD 64
#define MROWS (BATCH*SEQ)   // 8192
#define NSTRIP (SEQ/32)     // 64
#define QSCALE 0.18033688011112042f  // 0.125 * log2(e): softmax in exp2 domain

typedef float f32x4  __attribute__((ext_vector_type(4)));
typedef float f32x16 __attribute__((ext_vector_type(16)));
typedef short s16x8  __attribute__((ext_vector_type(8)));

__device__ __forceinline__ f32x4 mfma16(s16x8 a, s16x8 b, f32x4 c) {
    return __builtin_amdgcn_mfma_f32_16x16x32_bf16(a, b, c, 0, 0, 0);
}
__device__ __forceinline__ f32x16 mfma32(s16x8 a, s16x8 b, f32x16 c) {
    return __builtin_amdgcn_mfma_f32_32x32x16_bf16(a, b, c, 0, 0, 0);
}

__device__ __forceinline__ unsigned short f2bf(float f) {
    __hip_bfloat16 h = __float2bfloat16(f);
    return __builtin_bit_cast(unsigned short, h);
}

__device__ __forceinline__ unsigned cvtpk(float lo, float hi) {
    unsigned r;
    asm("v_cvt_pk_bf16_f32 %0, %1, %2" : "=v"(r) : "v"(lo), "v"(hi));
    return r;
}

__device__ __forceinline__ void plane_swap(unsigned &a, unsigned &b) {
    asm("v_permlane32_swap_b32 %0, %1" : "+v"(a), "+v"(b));
}

__device__ __forceinline__ s16x8 frag4(unsigned a, unsigned b, unsigned c, unsigned d) {
    union { unsigned u[4]; s16x8 f; } x;
    x.u[0] = a; x.u[1] = b; x.u[2] = c; x.u[3] = d;
    return x.f;
}

__device__ __forceinline__ float exp2r(float x) {   // raw v_exp_f32 (2^x)
    float r;
    asm("v_exp_f32 %0, %1" : "=v"(r) : "v"(x));
    return r;
}
__device__ __forceinline__ float max3f(float a, float b, float c) {
    float r;
    asm("v_max3_f32 %0, %1, %2, %3" : "=v"(r) : "v"(a), "v"(b), "v"(c));
    return r;
}

// ---------------- fp32 -> bf16 conversion: one launch for all 5 tensors ----------------
__global__ void cvt_all(const float* __restrict__ x,
                        const float* __restrict__ w0, const float* __restrict__ w1,
                        const float* __restrict__ w2, const float* __restrict__ w3,
                        unsigned short* __restrict__ xb,
                        unsigned short* __restrict__ o0, unsigned short* __restrict__ o1,
                        unsigned short* __restrict__ o2, unsigned short* __restrict__ o3,
                        int nx4, int nw4) {
    int i = blockIdx.x * blockDim.x + threadIdx.x;
    const float* in; unsigned short* out; int n;
    switch (blockIdx.y) {
        case 0:  in = x;  out = xb; n = nx4; break;
        case 1:  in = w0; out = o0; n = nw4; break;
        case 2:  in = w1; out = o1; n = nw4; break;
        case 3:  in = w2; out = o2; n = nw4; break;
        default: in = w3; out = o3; n = nw4; break;
    }
    if (i >= n) return;
    float4 v = reinterpret_cast<const float4*>(in)[i];
    ushort4 o;
    o.x = f2bf(v.x); o.y = f2bf(v.y); o.z = f2bf(v.z); o.w = f2bf(v.w);
    reinterpret_cast<ushort4*>(out)[i] = o;
}

#define GLDS(g, s) __builtin_amdgcn_global_load_lds((const __attribute__((address_space(1))) void*)(g), \
                       (__attribute__((address_space(3))) void*)(s), 16, 0, 0)

// ---------------- fused QKV GEMM (2-phase double-buffered staging) ----------------
// grid (24, 64): blockIdx.x = seg(0..2)*8 + n-tile; seg 0->Q, 1->K, 2->V.
__global__ __launch_bounds__(256) void gemm_qkv(const unsigned short* __restrict__ A,
                                                const unsigned short* __restrict__ wqb,
                                                const unsigned short* __restrict__ wkb,
                                                const unsigned short* __restrict__ wvb,
                                                const float* __restrict__ bq,
                                                const float* __restrict__ bk,
                                                const float* __restrict__ bv,
                                                unsigned short* __restrict__ qB,
                                                unsigned short* __restrict__ kB,
                                                unsigned short* __restrict__ vtB) {
    __shared__ unsigned short sA0[128*32];
    __shared__ unsigned short sB0[128*32];
    __shared__ unsigned short sA1[128*32];
    __shared__ unsigned short sB1[128*32];
    const int tid = threadIdx.x;
    const int w  = tid >> 6, l = tid & 63;
    const int lg = l >> 4,  lr = l & 15;
    const int nb  = blockIdx.x;
    const int seg = nb >> 3;
    const int mBase = blockIdx.y * 128;
    const int nBase = (nb & 7) * 128;
    const unsigned short* Bw = (seg == 0) ? wqb : (seg == 1) ? wkb : wvb;
    const float* bias = (seg == 0) ? bq : (seg == 1) ? bk : bv;
    const int wr = w >> 1, wc = w & 1;
    const int srow = l >> 2;
    const int sk0  = (l & 3) * 8;
    const bool segV = (seg == 2);

    f32x4 acc[4][4] = {};

    auto STAGE = [&](unsigned short* dA, unsigned short* dB, int kb) {
        #pragma unroll
        for (int rr = 0; rr < 2; ++rr) {
            const int chunk = w + rr * 4;                 // wave-uniform
            const unsigned short* ga = A  + (size_t)(mBase + chunk*16 + srow) * EMB + kb + sk0;
            GLDS(ga, &dA[chunk * 512]);
            const unsigned short* gb = Bw + (size_t)(nBase + chunk*16 + srow) * EMB + kb + sk0;
            GLDS(gb, &dB[chunk * 512]);
        }
    };
    auto COMPUTE = [&](const unsigned short* dA, const unsigned short* dB) {
        s16x8 af[4], bf[4];
        #pragma unroll
        for (int mi = 0; mi < 4; ++mi)
            af[mi] = *reinterpret_cast<const s16x8*>(&dA[(wr*64 + mi*16 + lr)*32 + lg*8]);
        #pragma unroll
        for (int ni = 0; ni < 4; ++ni)
            bf[ni] = *reinterpret_cast<const s16x8*>(&dB[(wc*64 + ni*16 + lr)*32 + lg*8]);
        if (segV) {
            #pragma unroll
            for (int mi = 0; mi < 4; ++mi)
                #pragma unroll
                for (int ni = 0; ni < 4; ++ni)
                    acc[ni][mi] = mfma16(bf[ni], af[mi], acc[ni][mi]);  // C^T
        } else {
            #pragma unroll
            for (int mi = 0; mi < 4; ++mi)
                #pragma unroll
                for (int ni = 0; ni < 4; ++ni)
                    acc[mi][ni] = mfma16(af[mi], bf[ni], acc[mi][ni]);
        }
    };

    STAGE(sA0, sB0, 0);
    __syncthreads();
    for (int kb = 0; kb < EMB; kb += 64) {
        STAGE(sA1, sB1, kb + 32);       // prefetch hides under COMPUTE
        COMPUTE(sA0, sB0);
        __syncthreads();                // drains mostly-complete prefetch
        if (kb + 64 < EMB) STAGE(sA0, sB0, kb + 64);
        COMPUTE(sA1, sB1);
        __syncthreads();
    }

    const int colBase = nBase + wc * 64;
    const int rowBase = mBase + wr * 64;
    if (!segV) {
        unsigned short* outp = seg ? kB : qB;
        const float oscale = seg ? 1.0f : QSCALE;
        #pragma unroll
        for (int ni = 0; ni < 4; ++ni) {
            const int col = colBase + ni*16 + lr;
            const float bv = bias[col];
            const int h = col >> 6, d = col & 63;
            const int inner = ((d >> 4) * 2 + ((d >> 3) & 1)) * 256 + (d & 7);
            #pragma unroll
            for (int mi = 0; mi < 4; ++mi) {
                #pragma unroll
                for (int r = 0; r < 4; ++r) {
                    const int gr = rowBase + mi*16 + lg*4 + r;
                    const int b = gr >> 11, sin_ = gr & 2047;
                    const int strip = sin_ >> 5, l31q = sin_ & 31;
                    outp[(size_t)(b*NH + h) * (SEQ*DHEAD) + strip*2048 + inner + l31q*8]
                        = f2bf((acc[mi][ni][r] + bv) * oscale);
                }
            }
        }
    } else {
        #pragma unroll
        for (int ni = 0; ni < 4; ++ni) {
            #pragma unroll
            for (int r = 0; r < 4; ++r) {
                const int n = colBase + ni*16 + lg*4 + r;
                const float bv = bias[n];
                const int h = n >> 6, d = n & 63;
                #pragma unroll
                for (int mi = 0; mi < 4; ++mi) {
                    const int tok = rowBase + mi*16 + lr;
                    const int b = tok >> 11, sv = tok & 2047;
                    const int kvt = sv >> 5, ks = (sv >> 4) & 1, hi2 = (sv >> 3) & 1, j = sv & 7;
                    vtB[(size_t)(b*NH + h) * (SEQ*DHEAD) + kvt*2048 + (ks*2 + hi2)*512 + d*8 + j]
                        = f2bf(acc[ni][mi][r] + bv);
                }
            }
        }
    }
}

// ---------------- output projection GEMM (2-phase, fp32 out + bias) ----------------
__global__ __launch_bounds__(256) void gemm_out(const unsigned short* __restrict__ A,
                                                const unsigned short* __restrict__ Bw,
                                                const float* __restrict__ bias,
                                                float* __restrict__ Out) {
    __shared__ unsigned short sA0[128*32];
    __shared__ unsigned short sB0[128*32];
    __shared__ unsigned short sA1[128*32];
    __shared__ unsigned short sB1[128*32];
    const int tid = threadIdx.x;
    const int w  = tid >> 6, l = tid & 63;
    const int lg = l >> 4,  lr = l & 15;
    const int mBase = blockIdx.y * 128;
    const int nBase = blockIdx.x * 128;
    const int wr = w >> 1, wc = w & 1;
    const int srow = l >> 2;
    const int sk0  = (l & 3) * 8;

    f32x4 acc[4][4] = {};

    auto STAGE = [&](unsigned short* dA, unsigned short* dB, int kb) {
        #pragma unroll
        for (int rr = 0; rr < 2; ++rr) {
            const int chunk = w + rr * 4;
            const unsigned short* ga = A  + (size_t)(mBase + chunk*16 + srow) * EMB + kb + sk0;
            GLDS(ga, &dA[chunk * 512]);
            const unsigned short* gb = Bw + (size_t)(nBase + chunk*16 + srow) * EMB + kb + sk0;
            GLDS(gb, &dB[chunk * 512]);
        }
    };
    auto COMPUTE = [&](const unsigned short* dA, const unsigned short* dB) {
        s16x8 af[4], bf[4];
        #pragma unroll
        for (int mi = 0; mi < 4; ++mi)
            af[mi] = *reinterpret_cast<const s16x8*>(&dA[(wr*64 + mi*16 + lr)*32 + lg*8]);
        #pragma unroll
        for (int ni = 0; ni < 4; ++ni)
            bf[ni] = *reinterpret_cast<const s16x8*>(&dB[(wc*64 + ni*16 + lr)*32 + lg*8]);
        #pragma unroll
        for (int mi = 0; mi < 4; ++mi)
            #pragma unroll
            for (int ni = 0; ni < 4; ++ni)
                acc[mi][ni] = mfma16(af[mi], bf[ni], acc[mi][ni]);
    };

    STAGE(sA0, sB0, 0);
    __syncthreads();
    for (int kb = 0; kb < EMB; kb += 64) {
        STAGE(sA1, sB1, kb + 32);
        COMPUTE(sA0, sB0);
        __syncthreads();
        if (kb + 64 < EMB) STAGE(sA0, sB0, kb + 64);
        COMPUTE(sA1, sB1);
        __syncthreads();
    }

    const int colBase = nBase + wc * 64;
    const int rowBase = mBase + wr * 64;
    #pragma unroll
    for (int ni = 0; ni < 4; ++ni) {
        const int col = colBase + ni*16 + lr;
        const float bv = bias[col];
        #pragma unroll
        for (int mi = 0; mi < 4; ++mi) {
            #pragma unroll
            for (int r = 0; r < 4; ++r) {
                const int gr = rowBase + mi*16 + lg*4 + r;
                Out[(size_t)gr * EMB + col] = acc[mi][ni][r] + bv;
            }
        }
    }
}

// ---------------- flash attention (causal), swapped-operand 32x32 MFMA ----------------
// 2 waves per block, SAME strip, adjacent heads: bh = (bx&31)*2 + wave.
// Per-wave state identical to the proven 1-wave kernel (VGPR ~84); perfect
// intra-block balance; strip-major dispatch order preserves K/V L2/L3 locality.
// 2048 workgroups -> each ~8 slots/CU now carries 16 waves/CU.
__global__ __launch_bounds__(128) void attn_fwd(const unsigned short* __restrict__ qb,
                                                const unsigned short* __restrict__ kb,
                                                const unsigned short* __restrict__ vb,
                                                unsigned short* __restrict__ ctx) {
    __shared__ __align__(16) unsigned sld[2][32*36];
    const int tid = threadIdx.x;
    const int wv_ = tid >> 6;
    const int l = tid & 63;
    const int l31 = l & 31, hi = l >> 5;
    const int hp = (int)blockIdx.x & 31;                    // head-pair 0..31
    const int strip = (NSTRIP - 1) - ((int)blockIdx.x >> 5); // heavy-first, strip-major
    const int bh = hp * 2 + wv_;
    const int q0 = strip * 32;
    const size_t hbase = (size_t)bh * SEQ * DHEAD;
    const unsigned short* qh = qb + hbase;
    const unsigned short* kh = kb + hbase;
    const unsigned short* vh = vb + hbase;

    s16x8 qf[4];
    #pragma unroll
    for (int s = 0; s < 4; ++s)
        qf[s] = *reinterpret_cast<const s16x8*>(&qh[strip*2048 + s*512 + l*8]);

    f32x16 o0 = {}, o1 = {};
    float m = -__builtin_inff(), lsum = 0.f;
    const int ntiles = strip + 1;

    s16x8 kfA[4], vfA[4], kfB[4], vfB[4];

    auto LOADKV = [&](s16x8* kf, s16x8* vf, int t) {
        const unsigned short* kp = kh + t*2048;
        #pragma unroll
        for (int s = 0; s < 4; ++s)
            kf[s] = *reinterpret_cast<const s16x8*>(&kp[s*512 + l*8]);
        const unsigned short* vp = vh + t*2048 + hi*512 + l31*8;
        #pragma unroll
        for (int ks = 0; ks < 2; ++ks) {
            vf[ks]     = *reinterpret_cast<const s16x8*>(&vp[ks*1024]);
            vf[2 + ks] = *reinterpret_cast<const s16x8*>(&vp[ks*1024 + 256]);
        }
    };

    auto BODY = [&](s16x8* kf, s16x8* vf, int t) {
        f32x16 sa = {};
        #pragma unroll
        for (int s = 0; s < 4; ++s) sa = mfma32(kf[s], qf[s], sa);

        if (t == strip) {  // diagonal tile: mask kv > q
            #pragma unroll
            for (int r = 0; r < 16; ++r) {
                const int kvloc = (r & 3) + 8*(r >> 2) + 4*hi;
                if (kvloc > l31) sa[r] = -__builtin_inff();
            }
        }

        const float a0 = max3f(sa[0],  sa[1],  sa[2]);
        const float a1 = max3f(sa[3],  sa[4],  sa[5]);
        const float a2 = max3f(sa[6],  sa[7],  sa[8]);
        const float a3 = max3f(sa[9],  sa[10], sa[11]);
        const float a4 = max3f(sa[12], sa[13], sa[14]);
        const float b0 = max3f(a0, a1, a2);
        const float b1 = max3f(a3, a4, sa[15]);
        float pm = fmaxf(b0, b1);
        pm = fmaxf(pm, __shfl_xor(pm, 32));

        float mn = m;
        if (!__all(pm <= m + 8.0f)) {        // T13 defer-max (log2 domain: p <= 256)
            mn = fmaxf(m, pm);
            const float fs = exp2r(m - mn);
            o0 *= fs; o1 *= fs; lsum *= fs;
            m = mn;
        }

        #pragma unroll
        for (int r = 0; r < 16; ++r) sa[r] = exp2r(sa[r] - mn);   // in-place

        const float s0 = sa[0]+sa[1],   s1 = sa[2]+sa[3],   s2 = sa[4]+sa[5],   s3 = sa[6]+sa[7];
        const float s4 = sa[8]+sa[9],   s5 = sa[10]+sa[11], s6 = sa[12]+sa[13], s7 = sa[14]+sa[15];
        const float t0 = s0+s1, t1 = s2+s3, t2 = s4+s5, t3 = s6+s7;
        float rs = (t0+t1) + (t2+t3);
        rs += __shfl_xor(rs, 32);
        lsum += rs;

        unsigned u[4], v[4];
        #pragma unroll
        for (int r2 = 0; r2 < 4; ++r2) {
            u[r2] = cvtpk(sa[4*r2 + 0], sa[4*r2 + 1]);
            v[r2] = cvtpk(sa[4*r2 + 2], sa[4*r2 + 3]);
        }
        plane_swap(u[0], u[1]); plane_swap(v[0], v[1]);
        plane_swap(u[2], u[3]); plane_swap(v[2], v[3]);
        const s16x8 pf0 = frag4(u[0], v[0], u[1], v[1]);
        const s16x8 pf1 = frag4(u[2], v[2], u[3], v[3]);

        o0 = mfma32(vf[0], pf0, o0);
        o0 = mfma32(vf[1], pf1, o0);
        o1 = mfma32(vf[2], pf0, o1);
        o1 = mfma32(vf[3], pf1, o1);
    };

    LOADKV(kfA, vfA, 0);
    int t = 0;
    for (; t + 1 < ntiles; t += 2) {
        LOADKV(kfB, vfB, t + 1);
        BODY(kfA, vfA, t);
        if (t + 2 < ntiles) LOADKV(kfA, vfA, t + 2);
        BODY(kfB, vfB, t + 1);
    }
    if (t < ntiles) BODY(kfA, vfA, t);

    // ---- epilogue: normalize, wave-local LDS transpose, coalesced store ----
    const float inv = 1.0f / lsum;
    unsigned* my = sld[wv_];
    #pragma unroll
    for (int dt = 0; dt < 2; ++dt) {
        #pragma unroll
        for (int r2 = 0; r2 < 4; ++r2) {
            const float e0 = (dt ? o1[4*r2+0] : o0[4*r2+0]) * inv;
            const float e1 = (dt ? o1[4*r2+1] : o0[4*r2+1]) * inv;
            const float e2 = (dt ? o1[4*r2+2] : o0[4*r2+2]) * inv;
            const float e3 = (dt ? o1[4*r2+3] : o0[4*r2+3]) * inv;
            const int col = 4*r2 + 2*hi + 16*dt;
            my[l31*36 + col]     = cvtpk(e0, e1);
            my[l31*36 + col + 1] = cvtpk(e2, e3);
        }
    }
    asm volatile("s_waitcnt lgkmcnt(0)" ::: "memory");
    __builtin_amdgcn_sched_barrier(0);
    const int row = l >> 1, half = l & 1;
    const unsigned* rp = &my[row*36 + half*16];
    const int b = bh >> 4, h = bh & 15;
    unsigned short* op = &ctx[((size_t)b*SEQ + q0 + row) * EMB + h*DHEAD + half*32];
    #pragma unroll
    for (int i = 0; i < 4; ++i) {
        uint4 d4 = *reinterpret_cast<const uint4*>(rp + i*4);
        *reinterpret_cast<uint4*>(op + i*8) = d4;
    }
}

// ---------------- launch ----------------
extern "C" void kernel_launch(void* const* d_in, const int* in_sizes, int n_in,
                              void* d_out, int out_size, void* d_ws, size_t ws_size,
                              hipStream_t stream) {
    const float* x  = (const float*)d_in[0];
    const float* wq = (const float*)d_in[1];
    const float* bq = (const float*)d_in[2];
    const float* wk = (const float*)d_in[3];
    const float* bk = (const float*)d_in[4];
    const float* wv = (const float*)d_in[5];
    const float* bv = (const float*)d_in[6];
    const float* wo = (const float*)d_in[7];
    const float* bo = (const float*)d_in[8];
    float* out = (float*)d_out;

    char* ws = (char*)d_ws;
    const size_t MB = 1ull << 20;
    unsigned short* xb  = (unsigned short*)(ws);            // 16 MB; reused as ctx later
    unsigned short* wqb = (unsigned short*)(ws + 16*MB);
    unsigned short* wkb = (unsigned short*)(ws + 18*MB);
    unsigned short* wvb = (unsigned short*)(ws + 20*MB);
    unsigned short* wob = (unsigned short*)(ws + 22*MB);
    unsigned short* qB  = (unsigned short*)(ws + 24*MB);    // fragment-ready, pre-scaled (exp2 domain)
    unsigned short* kB  = (unsigned short*)(ws + 40*MB);    // fragment-ready
    unsigned short* vtB = (unsigned short*)(ws + 56*MB);    // fragment-ready V^T
    unsigned short* ctx = xb;

    const int nx4 = MROWS * EMB / 4;
    const int nw4 = EMB * EMB / 4;
    cvt_all<<<dim3((nx4 + 255)/256, 5), 256, 0, stream>>>(x, wq, wk, wv, wo,
                                                          xb, wqb, wkb, wvb, wob, nx4, nw4);

    gemm_qkv<<<dim3(24, MROWS/128), 256, 0, stream>>>(xb, wqb, wkb, wvb, bq, bk, bv, qB, kB, vtB);

    attn_fwd<<<dim3(NSTRIP * 32), 128, 0, stream>>>(qB, kB, vtB, ctx);

    gemm_out<<<dim3(EMB/128, MROWS/128), 256, 0, stream>>>(ctx, wob, bo, out);
}